// Round 8
// baseline (441.234 us; speedup 1.0000x reference)
//
#include <hip/hip_runtime.h>
#include <math.h>

// z_e (8,4096,256) f32, codebook (1024,256) f32. M=32768, D=256, K=1024.
// out (f32, concat): z_q[8388608] | similarity[33554432] | ids[32768] | loss[1]
#define SIM_OFF  8388608
#define IDS_OFF  41943040
#define LOSS_OFF 41975808

// ws layout (bytes):
//   0       ne[1024] f32
//   4096    rse[1024] f32 (1/sqrt(ne))
//   8192    rsz[32768] f32 (1/sqrt(nz))
//   139264  ccount[32768] u32 (zeroed by ze_prep)
//   270336  cbhi 1024x256 bf16 (524288 B)
//   794624  cblo 1024x256 bf16 (524288 B)
//   1318912 cand[32768][32] u64 (8 MB)  -> ends 9707520
#define NE_F      0
#define RSE_F     1024
#define RSZ_F     2048
#define CCOUNT_B  139264
#define CBHI_B    270336
#define CBLO_B    794624
#define CAND_B    1318912
#define CAND_CAP  32
#define MARGIN    2.0f

typedef __attribute__((ext_vector_type(8))) short bf16x8;
typedef __attribute__((ext_vector_type(4))) float f32x4;

__device__ __forceinline__ unsigned short bf16_rne(float x) {
  unsigned u = __float_as_uint(x);
  unsigned r = u + 0x7FFFu + ((u >> 16) & 1u);
  return (unsigned short)(r >> 16);
}
__device__ __forceinline__ float bf16_to_f(unsigned short h) {
  return __uint_as_float((unsigned)h << 16);
}
__device__ __forceinline__ unsigned long long packkey(float d, int idx) {
  unsigned u = __float_as_uint(d);
  u ^= (u & 0x80000000u) ? 0xFFFFFFFFu : 0x80000000u;  // order-preserving
  return ((unsigned long long)u << 32) | (unsigned)idx;
}
__device__ __forceinline__ float unpack_dist(unsigned long long k) {
  unsigned u = (unsigned)(k >> 32);
  u ^= (u & 0x80000000u) ? 0x80000000u : 0xFFFFFFFFu;
  return __uint_as_float(u);
}

// ---- codebook: ne, rse, hi/lo bf16 planes; zero loss ----
__global__ __launch_bounds__(256) void cb_prep(const float* __restrict__ cb,
                                               float* __restrict__ ws,
                                               float* __restrict__ out) {
  int row = blockIdx.x * 4 + (threadIdx.x >> 6);
  int l = threadIdx.x & 63;
  float4 v = ((const float4*)cb)[row * 64 + l];
  float s = v.x * v.x + v.y * v.y + v.z * v.z + v.w * v.w;
  #pragma unroll
  for (int m = 1; m < 64; m <<= 1) s += __shfl_xor(s, m, 64);
  ushort4 hi, lo;
  hi.x = bf16_rne(v.x); lo.x = bf16_rne(v.x - bf16_to_f(hi.x));
  hi.y = bf16_rne(v.y); lo.y = bf16_rne(v.y - bf16_to_f(hi.y));
  hi.z = bf16_rne(v.z); lo.z = bf16_rne(v.z - bf16_to_f(hi.z));
  hi.w = bf16_rne(v.w); lo.w = bf16_rne(v.w - bf16_to_f(hi.w));
  ((ushort4*)((char*)ws + CBHI_B))[row * 64 + l] = hi;
  ((ushort4*)((char*)ws + CBLO_B))[row * 64 + l] = lo;
  if (l == 0) {
    ws[NE_F + row] = s;
    ws[RSE_F + row] = 1.0f / sqrtf(s);
  }
  if (blockIdx.x == 0 && threadIdx.x == 0) out[LOSS_OFF] = 0.0f;
}

// ---- z_e: rsz + hi/lo planes into z_q region; zero ccount ----
__global__ __launch_bounds__(256) void ze_prep(const float* __restrict__ ze,
                                               float* __restrict__ ws,
                                               float* __restrict__ out) {
  int row = blockIdx.x * 4 + (threadIdx.x >> 6);
  int l = threadIdx.x & 63;
  float4 v = ((const float4*)ze)[(size_t)row * 64 + l];
  float s = v.x * v.x + v.y * v.y + v.z * v.z + v.w * v.w;
  #pragma unroll
  for (int m = 1; m < 64; m <<= 1) s += __shfl_xor(s, m, 64);
  ushort4 hi, lo;
  hi.x = bf16_rne(v.x); lo.x = bf16_rne(v.x - bf16_to_f(hi.x));
  hi.y = bf16_rne(v.y); lo.y = bf16_rne(v.y - bf16_to_f(hi.y));
  hi.z = bf16_rne(v.z); lo.z = bf16_rne(v.z - bf16_to_f(hi.z));
  hi.w = bf16_rne(v.w); lo.w = bf16_rne(v.w - bf16_to_f(hi.w));
  unsigned short* zehi = (unsigned short*)out;
  unsigned short* zelo = (unsigned short*)out + 8388608;
  ((ushort4*)zehi)[(size_t)row * 64 + l] = hi;
  ((ushort4*)zelo)[(size_t)row * 64 + l] = lo;
  if (l == 0) {
    ws[RSZ_F + row] = 1.0f / sqrtf(s);
    ((unsigned*)((char*)ws + CCOUNT_B))[row] = 0u;
  }
}

// ---- split-MFMA GEMM (round-6 staging: pad-5 LDS, reg->ds_write) +
// fused epilogue: sim write, per-(row,64col) min, candidate append. ----
__global__ __launch_bounds__(256) void vq_gemm(float* ws, float* out) {
  __shared__ uint4 lds4[2560];            // Ahi 0 | Alo 640 | Bhi 1280 | Blo 1920
  __shared__ float rszS[128], rseS[128], neS[128];

  const int t = threadIdx.x;
  const int bx = blockIdx.x & 7;          // 8 code tiles
  const int by = blockIdx.x >> 3;         // 256 row tiles
  const int m0 = by * 128, n0 = bx * 128;
  const int l = t & 63, w = t >> 6;
  const int wr = w >> 1, wc = w & 1;
  const int ln = l & 15, kg = l >> 4;

  const uint4* zehi4 = (const uint4*)out;                       // row = 32 u4
  const uint4* zelo4 = (const uint4*)((const char*)out + 16777216);
  const uint4* cbhi4 = (const uint4*)((const char*)ws + CBHI_B);
  const uint4* cblo4 = (const uint4*)((const char*)ws + CBLO_B);
  unsigned* ccount = (unsigned*)((char*)ws + CCOUNT_B);
  unsigned long long* cand = (unsigned long long*)((char*)ws + CAND_B);
  float* sim_out = out + SIM_OFF;

  if (t < 128) {
    rszS[t] = ws[RSZ_F + m0 + t];
  } else {
    rseS[t - 128] = ws[RSE_F + n0 + (t - 128)];
    neS[t - 128] = ws[NE_F + n0 + (t - 128)];
  }

  f32x4 acc[4][4];
  #pragma unroll
  for (int i = 0; i < 4; ++i)
    #pragma unroll
    for (int j = 0; j < 4; ++j) acc[i][j] = (f32x4){0.f, 0.f, 0.f, 0.f};

  for (int kt = 0; kt < 8; ++kt) {
    __syncthreads();
    #pragma unroll
    for (int i = 0; i < 2; ++i) {
      int f2 = i * 256 + t;
      int r = f2 >> 2, q = f2 & 3;
      int gsrcA = (m0 + r) * 32 + kt * 4 + q;
      int gsrcB = (n0 + r) * 32 + kt * 4 + q;
      int dst = r * 5 + q;
      lds4[dst]        = zehi4[gsrcA];
      lds4[640 + dst]  = zelo4[gsrcA];
      lds4[1280 + dst] = cbhi4[gsrcB];
      lds4[1920 + dst] = cblo4[gsrcB];
    }
    __syncthreads();

    bf16x8 ah[4], al[4], bh[4], bl[4];
    #pragma unroll
    for (int fm = 0; fm < 4; ++fm) {
      int rl = wr * 64 + fm * 16 + ln;
      ah[fm] = *(const bf16x8*)&lds4[rl * 5 + kg];
      al[fm] = *(const bf16x8*)&lds4[640 + rl * 5 + kg];
    }
    #pragma unroll
    for (int fn = 0; fn < 4; ++fn) {
      int cl = wc * 64 + fn * 16 + ln;
      bh[fn] = *(const bf16x8*)&lds4[1280 + cl * 5 + kg];
      bl[fn] = *(const bf16x8*)&lds4[1920 + cl * 5 + kg];
    }
    #pragma unroll
    for (int fm = 0; fm < 4; ++fm)
      #pragma unroll
      for (int fn = 0; fn < 4; ++fn) {
        acc[fm][fn] = __builtin_amdgcn_mfma_f32_16x16x32_bf16(ah[fm], bh[fn], acc[fm][fn], 0, 0, 0);
        acc[fm][fn] = __builtin_amdgcn_mfma_f32_16x16x32_bf16(ah[fm], bl[fn], acc[fm][fn], 0, 0, 0);
        acc[fm][fn] = __builtin_amdgcn_mfma_f32_16x16x32_bf16(al[fm], bh[fn], acc[fm][fn], 0, 0, 0);
      }
  }

  // epilogue: per (fm,r) row: sim stores, dists, 64-col min, candidate append.
  // C/D layout: col=l&15, row=(l>>4)*4+reg (m89-verified).
  #pragma unroll
  for (int fm = 0; fm < 4; ++fm) {
    #pragma unroll
    for (int r = 0; r < 4; ++r) {
      int rl = wr * 64 + fm * 16 + kg * 4 + r;
      int grow = m0 + rl;
      float rsz = rszS[rl];
      float d[4];
      int c[4];
      #pragma unroll
      for (int fn = 0; fn < 4; ++fn) {
        int cl = wc * 64 + fn * 16 + ln;
        float dot = acc[fm][fn][r];
        sim_out[(size_t)grow * 1024 + n0 + cl] = dot * rsz * rseS[cl];
        d[fn] = fmaf(-2.0f, dot, neS[cl]);
        c[fn] = n0 + cl;
      }
      float mn = fminf(fminf(d[0], d[1]), fminf(d[2], d[3]));
      int mc = (d[0] == mn) ? c[0] : (d[1] == mn) ? c[1] : (d[2] == mn) ? c[2] : c[3];
      unsigned long long key = packkey(mn, mc);
      #pragma unroll
      for (int m = 1; m < 16; m <<= 1) {   // min over the 16 ln lanes (same kg)
        unsigned long long o = __shfl_xor(key, m, 64);
        key = o < key ? o : key;
      }
      float thr = unpack_dist(key) + MARGIN;
      #pragma unroll
      for (int fn = 0; fn < 4; ++fn) {
        if (d[fn] <= thr) {
          unsigned pos = atomicAdd(&ccount[grow], 1u);
          if (pos < CAND_CAP)
            cand[(size_t)grow * CAND_CAP + pos] = packkey(d[fn], c[fn]);
        }
      }
    }
  }
}

// ---- pass2: wave per row. Read candidates only (no sim): wave-min ->
// filter vs min+MARGIN -> exact double refine -> z_q, ids, loss. ----
__global__ __launch_bounds__(256) void vq_pass2(const float* __restrict__ ze,
                                                const float* __restrict__ cb,
                                                const float* __restrict__ ws,
                                                float* __restrict__ out) {
  __shared__ float ps[4];
  const int t = threadIdx.x, w = t >> 6, l = t & 63;
  const int row = blockIdx.x * 4 + w;
  const float4* cb4 = (const float4*)cb;
  const unsigned* ccount = (const unsigned*)((const char*)ws + CCOUNT_B);
  const unsigned long long* cand =
      (const unsigned long long*)((const char*)ws + CAND_B);

  float4 z4 = ((const float4*)ze)[(size_t)row * 64 + l];

  unsigned cnt = ccount[row];
  cnt = cnt < CAND_CAP ? cnt : CAND_CAP;
  unsigned long long key =
      ((unsigned)l < cnt) ? cand[(size_t)row * CAND_CAP + l] : ~0ull;
  unsigned long long kmin = key;
  #pragma unroll
  for (int m = 1; m < 64; m <<= 1) {
    unsigned long long o = __shfl_xor(kmin, m, 64);
    kmin = o < kmin ? o : kmin;
  }
  float thr = unpack_dist(kmin) + MARGIN;
  bool active = ((unsigned)l < cnt) && (unpack_dist(key) <= thr);

  double bestd = 1e300;
  int bestid = 0;
  unsigned long long wb = __ballot(active);
  while (wb) {
    int src = __ffsll((unsigned long long)wb) - 1;
    wb &= wb - 1;
    unsigned long long k = __shfl((long long)key, src, 64);
    int cid = (int)(unsigned)(k & 0xFFFFFFFFull);
    float4 c4 = cb4[(size_t)cid * 64 + l];
    double p = (double)z4.x * c4.x + (double)z4.y * c4.y +
               (double)z4.z * c4.z + (double)z4.w * c4.w;
    #pragma unroll
    for (int mm = 1; mm < 64; mm <<= 1) p += __shfl_xor(p, mm, 64);
    double dist = (double)ws[NE_F + cid] - 2.0 * p;
    if (dist < bestd || (dist == bestd && cid < bestid)) {
      bestd = dist; bestid = cid;
    }
  }

  float4 q4 = cb4[(size_t)bestid * 64 + l];
  ((float4*)out)[(size_t)row * 64 + l] = q4;
  float dx = z4.x - q4.x, dy = z4.y - q4.y, dz = z4.z - q4.z, dw = z4.w - q4.w;
  float s = dx * dx + dy * dy + dz * dz + dw * dw;
  #pragma unroll
  for (int m = 1; m < 64; m <<= 1) s += __shfl_xor(s, m, 64);
  if (l == 0) {
    ps[w] = sqrtf(s);
    out[IDS_OFF + row] = (float)bestid;
  }
  __syncthreads();
  if (t == 0)
    atomicAdd(out + LOSS_OFF, (ps[0] + ps[1] + ps[2] + ps[3]) * (1.25f / 32768.0f));
}

extern "C" void kernel_launch(void* const* d_in, const int* in_sizes, int n_in,
                              void* d_out, int out_size, void* d_ws, size_t ws_size,
                              hipStream_t stream) {
  const float* ze = (const float*)d_in[0];
  const float* cb = (const float*)d_in[1];
  float* out = (float*)d_out;
  float* ws = (float*)d_ws;

  cb_prep<<<256, 256, 0, stream>>>(cb, ws, out);
  ze_prep<<<8192, 256, 0, stream>>>(ze, ws, out);
  vq_gemm<<<2048, 256, 0, stream>>>(ws, out);
  vq_pass2<<<8192, 256, 0, stream>>>(ze, cb, ws, out);
}